// Round 1
// 284.411 us; speedup vs baseline: 1.0869x; 1.0869x over previous
//
#include <hip/hip_runtime.h>
#include <hip/hip_bf16.h>
#include <cstddef>

// ---------------------------------------------------------------------------
// 3-layer MPNN, N=50000, E=800000, D=128, OUT=32.
// R13 (= R12 + fused_gemm de-latency): fused_gemm was latency-serialized
// (56 VGPRs -> 1 Wswz load in flight, 64 x ~200cyc L2 waits/wave; MfmaUtil
// 2.5%). Now: Wswz staged to LDS once per block (64KB, ds_read_b128 w/ imm
// offsets), all 8 A-fragment loads issued before the staging barrier, and
// tanhf replaced by 1-2*rcp(exp2(2log2e*x)+1) (5 insts vs ~25; exact
// saturation at +-inf). mfma_gemm_out: all loads hoisted (MLP).
// Binning/CSR/aggregate unchanged from R12.
//   g = Sigma_in w*h[src]; h' = tanh([g|h]@[Wm;Wu]^T+bu); out = h3@Wout^T+b.
// CSR entry: (src:u16 | w:bf16<<16).
// ---------------------------------------------------------------------------

typedef __attribute__((ext_vector_type(8))) short short8;
typedef __attribute__((ext_vector_type(4))) float f32x4;
typedef unsigned short ushort_t;
typedef unsigned int uint_t;

#define BSH 8               // bucket shift: 256 nodes per bucket
#define BSZ 256             // nodes per bucket
#define CAPB 6144           // staged entries per bucket (mean 4096, >30 sigma)
#define TSTRIDE 16          // tails counter stride in ints (64B line each)
#define EPB 2048            // edges per bin block

__device__ inline ushort_t f2bf(float f) {  // round-to-nearest-even
    uint_t u = __float_as_uint(f);
    uint_t r = u + 0x7FFFu + ((u >> 16) & 1u);
    return (ushort_t)(r >> 16);
}
__device__ inline float bf_lo(uint_t u) { return __uint_as_float(u << 16); }
__device__ inline float bf_hi(uint_t u) { return __uint_as_float(u & 0xFFFF0000u); }
__device__ inline uint_t packbf(float a, float b) {
    return (uint_t)f2bf(a) | ((uint_t)f2bf(b) << 16);
}

// fast tanh: 1 - 2/(exp2(2*log2e*x)+1); saturates correctly at +-inf.
// error ~1e-7 rel (v_exp+v_rcp) -- far below bf16 output quantum.
__device__ inline float fast_tanh(float x) {
    float e = __builtin_amdgcn_exp2f(x * 2.8853900817779268f);
    return 1.f - 2.f * __builtin_amdgcn_rcpf(e + 1.f);
}

// flag=1 -> int32 [2][E]; flag=0 -> int64 [2][E] (vectorized low-word read)
__device__ inline int get_dst(const int* __restrict__ ei, int e, int E, int f) {
    if (f) return ei[E + e];
    return ((const int2*)ei)[(size_t)E + e].x;
}
__device__ inline int get_src(const int* __restrict__ ei, int e, int E, int f) {
    if (f) return ei[e];
    return ((const int2*)ei)[e].x;
}

// ---------------------------------------------------------------------------
// Fused setup: zero tails+cursor | detect idx layout | swizzled bf16 weights
// | x -> bf16.
// wswz[l]: flat ((ct*8+ks)*64+lane)*8+j <- Wcat[(ct*16+(lane&15))][ks*32+
//   (lane>>4)*8+j]  (Wcat = [Wm | Wu], K=256)
// woswz:   flat ((ct*4+ks)*64+lane)*8+j <- Wout[...]  (K=128, ct<2)
// ---------------------------------------------------------------------------
struct SetupArgs {
    const float* Wm0; const float* Wu0;
    const float* Wm1; const float* Wu1;
    const float* Wm2; const float* Wu2;
    const float* Wout;
    const float* x; const int* ei;
    ushort_t* wswz;    // 3 * 32768
    ushort_t* woswz;   // 4096
    ushort_t* xb;      // N*128
    int* tails;        // NB*TSTRIDE + cursor (zeroed together)
    int* flag;
    int N, E, TI;
    int ZT, WB, XB;
};
__global__ __launch_bounds__(256) void setup_kernel(SetupArgs a) {
    int bx = blockIdx.x, t = threadIdx.x;
    if (bx < a.ZT) {
        int i = bx * 256 + t;
        if (i < a.TI) a.tails[i] = 0;
        return;
    }
    bx -= a.ZT;
    if (bx == 0) {
        __shared__ int any;
        if (t == 0) any = 0;
        __syncthreads();
        int n = a.E < 2048 ? a.E : 2048;
        for (int i = t; i < n; i += 256)
            if (a.ei[2 * i + 1] != 0) any = 1;
        __syncthreads();
        if (t == 0) a.flag[0] = any;
        return;
    }
    bx -= 1;
    if (bx < a.WB) {
        int i = bx * 256 + t;
        if (i < 3 * 32768) {
            int l = i >> 15, r2 = i & 32767;
            int ct = r2 >> 12, ks = (r2 >> 9) & 7, lane = (r2 >> 3) & 63, j = r2 & 7;
            int col = ct * 16 + (lane & 15);
            int k = ks * 32 + (lane >> 4) * 8 + j;
            const float* Wm = l == 0 ? a.Wm0 : (l == 1 ? a.Wm1 : a.Wm2);
            const float* Wu = l == 0 ? a.Wu0 : (l == 1 ? a.Wu1 : a.Wu2);
            float v = k < 128 ? Wm[col * 128 + k] : Wu[col * 128 + (k - 128)];
            a.wswz[(size_t)l * 32768 + r2] = f2bf(v);
        } else if (i < 3 * 32768 + 4096) {
            int r2 = i - 3 * 32768;
            int ct = r2 >> 11, ks = (r2 >> 9) & 3, lane = (r2 >> 3) & 63, j = r2 & 7;
            int col = ct * 16 + (lane & 15);
            int k = ks * 32 + (lane >> 4) * 8 + j;
            a.woswz[r2] = f2bf(a.Wout[col * 128 + k]);
        }
        return;
    }
    bx -= a.WB;
    {
        int j = bx * 256 + t;
        if (j < a.N * 32) {
            float4 v = *(const float4*)(a.x + (size_t)j * 4);
            uint2 o;
            o.x = packbf(v.x, v.y);
            o.y = packbf(v.z, v.w);
            *(uint2*)(a.xb + (size_t)j * 4) = o;
        }
    }
}

// ---------------------------------------------------------------------------
// Phase A: LDS multi-split binning (one global atomic per (block,bucket)).
// bucket = dst>>8 (256 nodes). ~77k reserve atomics total.
// ---------------------------------------------------------------------------
__global__ __launch_bounds__(256) void bin_kernel(
    const int* __restrict__ ei, const float* __restrict__ ew,
    const int* __restrict__ flag, int* __restrict__ tails,
    uint2* __restrict__ staged, int E, int NB) {
    __shared__ uint2 ent[EPB];           // 16 KB
    __shared__ int cnt[256], cur[256], runbase[256];
    const int tid = threadIdx.x;
    const int e0 = blockIdx.x * EPB;
    const int nE = (E - e0) < EPB ? (E - e0) : EPB;
    const int f = flag[0];
    cnt[tid] = 0;
    cur[tid] = 0;
    __syncthreads();
    for (int i = tid; i < nE; i += 256) {
        int e = e0 + i;
        int s = get_src(ei, e, E, f);
        int d = get_dst(ei, e, E, f);
        uint2 v;
        v.x = (uint_t)s | ((uint_t)f2bf(ew[e]) << 16);
        v.y = (uint_t)d;
        ent[i] = v;
        atomicAdd(&cnt[d >> BSH], 1);    // LDS atomic
    }
    __syncthreads();
    if (tid < NB) {
        int c = cnt[tid];
        runbase[tid] = c ? atomicAdd(&tails[tid * TSTRIDE], c) : 0;
    }
    __syncthreads();
    for (int i = tid; i < nE; i += 256) {
        uint2 v = ent[i];
        int d = (int)v.y;
        int b = d >> BSH;
        int lp = atomicAdd(&cur[b], 1);  // LDS atomic
        int gp = runbase[b] + lp;
        if (gp < CAPB) {
            uint2 o;
            o.x = v.x;
            o.y = (uint_t)(d & (BSZ - 1));
            staged[(size_t)b * CAPB + gp] = o;
        }
    }
}

// ---------------------------------------------------------------------------
// Phase B: one block per bucket. Self-allocates the bucket's contiguous CSR
// region via a global cursor (bucket order arbitrary -- only rowspans
// matter). LDS hist (256 nodes) -> LDS excl scan -> LDS image -> coalesced
// flush. Writes rowdeg[node] = int2{beg, end}.
// ---------------------------------------------------------------------------
__global__ __launch_bounds__(256) void place_kernel(
    const uint2* __restrict__ staged, const int* __restrict__ tails,
    int* __restrict__ cursor, uint_t* __restrict__ csr,
    int2* __restrict__ rowdeg, int N) {
    __shared__ int cnt[256], cur[256], excl[256], sm[256];
    __shared__ int baseSh;
    __shared__ uint_t outb[CAPB];        // 24 KB
    const int b = blockIdx.x, tid = threadIdx.x;
    const int node0 = b << BSH;
    int tot = tails[b * TSTRIDE];
    tot = tot < CAPB ? tot : CAPB;
    cnt[tid] = 0;
    __syncthreads();
    const uint2* sp = staged + ((size_t)b * CAPB);
    for (int i = tid; i < tot; i += 256) atomicAdd(&cnt[sp[i].y], 1);
    __syncthreads();
    int c0 = cnt[tid];
    sm[tid] = c0;
    __syncthreads();
    for (int o = 1; o < 256; o <<= 1) {
        int v = tid >= o ? sm[tid - o] : 0;
        __syncthreads();
        sm[tid] += v;
        __syncthreads();
    }
    if (tid == 255) baseSh = atomicAdd(cursor, sm[255]);
    excl[tid] = sm[tid] - c0;
    cur[tid] = 0;
    __syncthreads();
    const int base = baseSh;
    for (int i = tid; i < tot; i += 256) {
        uint2 e = sp[i];
        int pos = excl[e.y] + atomicAdd(&cur[e.y], 1);
        outb[pos] = e.x;
    }
    __syncthreads();
    for (int i = tid; i < tot; i += 256) csr[base + i] = outb[i];
    if (node0 + tid < N) {
        int2 be;
        be.x = base + excl[tid];
        be.y = base + excl[tid] + c0;
        rowdeg[node0 + tid] = be;
    }
}

// ---------------------------------------------------------------------------
// Aggregate: g[d] = Sigma_{in(d)} w*h[src]. One 64-lane wave per node.
// lane = slot(0..7)*8 + f8(0..7); lane owns 16 feats via 2x uint4 loads.
// ---------------------------------------------------------------------------
__global__ __launch_bounds__(256) void aggregate_g(
    const uint_t* __restrict__ csr, const int2* __restrict__ rowdeg,
    const ushort_t* __restrict__ h, ushort_t* __restrict__ g, int N) {
    int node = (blockIdx.x * 256 + threadIdx.x) >> 6;
    if (node >= N) return;
    int lane = threadIdx.x & 63;
    int slot = lane >> 3, f8 = lane & 7;
    int2 be = rowdeg[node];
    int beg = be.x, end = be.y;
    float s[16];
#pragma unroll
    for (int k = 0; k < 16; ++k) s[k] = 0.f;
    for (int j = beg + slot; j < end; j += 8) {
        uint_t p = csr[j];
        float w = bf_hi(p);
        const ushort_t* row = h + (size_t)(p & 0xFFFFu) * 128 + f8 * 16;
        uint4 v0 = *(const uint4*)(row);
        uint4 v1 = *(const uint4*)(row + 8);
        s[0] += w * bf_lo(v0.x);  s[1] += w * bf_hi(v0.x);
        s[2] += w * bf_lo(v0.y);  s[3] += w * bf_hi(v0.y);
        s[4] += w * bf_lo(v0.z);  s[5] += w * bf_hi(v0.z);
        s[6] += w * bf_lo(v0.w);  s[7] += w * bf_hi(v0.w);
        s[8] += w * bf_lo(v1.x);  s[9] += w * bf_hi(v1.x);
        s[10] += w * bf_lo(v1.y); s[11] += w * bf_hi(v1.y);
        s[12] += w * bf_lo(v1.z); s[13] += w * bf_hi(v1.z);
        s[14] += w * bf_lo(v1.w); s[15] += w * bf_hi(v1.w);
    }
#pragma unroll
    for (int k = 0; k < 16; ++k) s[k] += __shfl_xor(s[k], 8, 64);
#pragma unroll
    for (int k = 0; k < 16; ++k) s[k] += __shfl_xor(s[k], 16, 64);
#pragma unroll
    for (int k = 0; k < 16; ++k) s[k] += __shfl_xor(s[k], 32, 64);
    if (slot == 0) {
        uint4 o0, o1;
        o0.x = packbf(s[0], s[1]);   o0.y = packbf(s[2], s[3]);
        o0.z = packbf(s[4], s[5]);   o0.w = packbf(s[6], s[7]);
        o1.x = packbf(s[8], s[9]);   o1.y = packbf(s[10], s[11]);
        o1.z = packbf(s[12], s[13]); o1.w = packbf(s[14], s[15]);
        ushort_t* gp = g + (size_t)node * 128 + f8 * 16;
        *(uint4*)(gp) = o0;
        *(uint4*)(gp + 8) = o1;
    }
}

// ---------------------------------------------------------------------------
// Layer GEMM: Hout[N,128] = tanh([G|H][N,256] @ Wswz + bu).
// Block 256 = 4 waves; wave owns 16 rows, all 128 cols.
// R13: Wswz staged to LDS (64KB) once per block; all 8 A-fragments issued
// before the staging barrier (latency hidden); B reads are ds_read_b128 with
// immediate offsets (conflict-free: lane i at byte 16*i within 1KB chunk).
// ---------------------------------------------------------------------------
__global__ __launch_bounds__(256) void fused_gemm(
    const ushort_t* __restrict__ G, const ushort_t* __restrict__ H,
    const ushort_t* __restrict__ Wswz, const float* __restrict__ bias,
    ushort_t* __restrict__ Hout, int N) {
    __shared__ ushort_t wl[32768];       // 64 KB -> 2 blocks/CU
    const int tid = threadIdx.x;
    const int lane = tid & 63;
    const int row0 = blockIdx.x * 64 + (tid >> 6) * 16;
    const int m = lane & 15, kg = lane >> 4;

    const ushort_t* ag = G + (size_t)(row0 + m) * 128 + kg * 8;
    const ushort_t* ah = H + (size_t)(row0 + m) * 128 + kg * 8;

    // issue all 8 A-fragment loads; latency hides under the staging barrier
    short8 a[8];
#pragma unroll
    for (int ks = 0; ks < 4; ++ks) a[ks] = *(const short8*)(ag + ks * 32);
#pragma unroll
    for (int ks = 0; ks < 4; ++ks) a[4 + ks] = *(const short8*)(ah + ks * 32);

    // stage full Wswz layer (64KB) into LDS: 16 chunks of 4KB (256 x 16B)
#pragma unroll
    for (int i = 0; i < 16; ++i) {
        uint4 v = *(const uint4*)(Wswz + ((size_t)i * 256 + tid) * 8);
        *(uint4*)(wl + (i * 256 + tid) * 8) = v;
    }
    __syncthreads();

    f32x4 acc[8];
#pragma unroll
    for (int ct = 0; ct < 8; ++ct) acc[ct] = (f32x4){0.f, 0.f, 0.f, 0.f};

#pragma unroll
    for (int ksp = 0; ksp < 8; ++ksp) {
#pragma unroll
        for (int ct = 0; ct < 8; ++ct) {
            short8 b = *(const short8*)(wl + ((ct * 8 + ksp) * 64 + lane) * 8);
            acc[ct] = __builtin_amdgcn_mfma_f32_16x16x32_bf16(a[ksp], b, acc[ct], 0, 0, 0);
        }
    }
    const int colL = lane & 15, rq = lane >> 4;
#pragma unroll
    for (int ct = 0; ct < 8; ++ct) {
        int col = ct * 16 + colL;
        float bv = bias[col];
#pragma unroll
        for (int reg = 0; reg < 4; ++reg) {
            int gr = row0 + rq * 4 + reg;
            if (gr < N) Hout[(size_t)gr * 128 + col] = f2bf(fast_tanh(acc[ct][reg] + bv));
        }
    }
}

// LDS-free output GEMM: out[N,32] = H[N,128] @ Woswz + bout (fp32).
// R13: all A/B loads hoisted (8 loads in flight instead of 1).
__global__ __launch_bounds__(256) void mfma_gemm_out(
    const ushort_t* __restrict__ H, const ushort_t* __restrict__ Wswz,
    const float* __restrict__ bias, float* __restrict__ C, int N) {
    const int tid = threadIdx.x;
    const int lane = tid & 63;
    const int row0 = blockIdx.x * 64 + (tid >> 6) * 16;
    const int m = lane & 15;
    const ushort_t* ah = H + (size_t)(row0 + m) * 128 + (lane >> 4) * 8;

    short8 a[4], b[8];
#pragma unroll
    for (int ks = 0; ks < 4; ++ks) a[ks] = *(const short8*)(ah + ks * 32);
#pragma unroll
    for (int ks = 0; ks < 4; ++ks) {
#pragma unroll
        for (int ct = 0; ct < 2; ++ct)
            b[ks * 2 + ct] = *(const short8*)(Wswz + ((ct * 4 + ks) * 64 + lane) * 8);
    }

    f32x4 acc[2];
#pragma unroll
    for (int ct = 0; ct < 2; ++ct) acc[ct] = (f32x4){0.f, 0.f, 0.f, 0.f};
#pragma unroll
    for (int ks = 0; ks < 4; ++ks) {
#pragma unroll
        for (int ct = 0; ct < 2; ++ct)
            acc[ct] = __builtin_amdgcn_mfma_f32_16x16x32_bf16(a[ks], b[ks * 2 + ct], acc[ct], 0, 0, 0);
    }
    const int colL = lane & 15, rq = lane >> 4;
#pragma unroll
    for (int ct = 0; ct < 2; ++ct) {
        int col = ct * 16 + colL;
        float bv = bias[col];
#pragma unroll
        for (int reg = 0; reg < 4; ++reg) {
            int gr = row0 + rq * 4 + reg;
            if (gr < N) C[(size_t)gr * 32 + col] = acc[ct][reg] + bv;
        }
    }
}

extern "C" void kernel_launch(void* const* d_in, const int* in_sizes, int n_in,
                              void* d_out, int out_size, void* d_ws, size_t ws_size,
                              hipStream_t stream) {
    const float* x   = (const float*)d_in[0];
    const int* ei    = (const int*)d_in[1];
    const float* ew  = (const float*)d_in[2];
    const float* Wm[3] = {(const float*)d_in[3], (const float*)d_in[6], (const float*)d_in[9]};
    const float* Wu[3] = {(const float*)d_in[4], (const float*)d_in[7], (const float*)d_in[10]};
    const float* bu[3] = {(const float*)d_in[5], (const float*)d_in[8], (const float*)d_in[11]};
    const float* Wout = (const float*)d_in[12];
    const float* bout = (const float*)d_in[13];
    float* out = (float*)d_out;

    const int N = in_sizes[0] / 128;
    const int E = in_sizes[2];
    const size_t NPAD = 50048;
    const int NB = (N + BSZ - 1) / BSZ;  // 196 buckets
    const int TI = NB * TSTRIDE + 16;    // tails + cursor (zeroed together)

    ushort_t* xb    = (ushort_t*)d_ws;              // [NPAD,128] bf16
    ushort_t* hA    = xb + NPAD * 128;
    ushort_t* hB    = hA + NPAD * 128;
    ushort_t* gbuf  = hB + NPAD * 128;
    ushort_t* wswz  = gbuf + NPAD * 128;            // 3*32768 bf16
    ushort_t* woswz = wswz + 3 * 32768;             // 4096 bf16
    int* flag       = (int*)(woswz + 4096);
    int* tails      = flag + 1;
    int* cursor     = tails + NB * TSTRIDE;         // inside zeroed TI range
    int* endp       = tails + TI;
    int2* rowdeg    = (int2*)(((uintptr_t)endp + 7) & ~(uintptr_t)7);
    uint2* staged   = (uint2*)(rowdeg + N + 8);
    uint_t* csr     = (uint_t*)(staged + (size_t)NB * CAPB);
    (void)ws_size;

    const int ZT = (TI + 255) / 256;
    const int WB = (3 * 32768 + 4096 + 255) / 256;  // 400
    const int XB = (N * 32 + 255) / 256;            // 6250
    const int gB = (E + EPB - 1) / EPB;             // 391
    const int gG = (N + 63) / 64;                   // 782
    const int gA = (N + 3) / 4;                     // 12500
    const int gO = (N + 63) / 64;                   // 782

    SetupArgs sa;
    sa.Wm0 = Wm[0]; sa.Wu0 = Wu[0];
    sa.Wm1 = Wm[1]; sa.Wu1 = Wu[1];
    sa.Wm2 = Wm[2]; sa.Wu2 = Wu[2];
    sa.Wout = Wout; sa.x = x; sa.ei = ei;
    sa.wswz = wswz; sa.woswz = woswz; sa.xb = xb;
    sa.tails = tails; sa.flag = flag;
    sa.N = N; sa.E = E; sa.TI = TI;
    sa.ZT = ZT; sa.WB = WB; sa.XB = XB;
    setup_kernel<<<ZT + 1 + WB + XB, 256, 0, stream>>>(sa);

    bin_kernel<<<gB, 256, 0, stream>>>(ei, ew, flag, tails, staged, E, NB);
    place_kernel<<<NB, 256, 0, stream>>>(staged, tails, cursor, csr, rowdeg, N);

    const ushort_t* hin[3] = {xb, hA, hB};
    ushort_t* hout[3] = {hA, hB, hA};
    for (int l = 0; l < 3; ++l) {
        aggregate_g<<<gA, 256, 0, stream>>>(csr, rowdeg, hin[l], gbuf, N);
        fused_gemm<<<gG, 256, 0, stream>>>(gbuf, hin[l], wswz + (size_t)l * 32768,
                                           bu[l], hout[l], N);
    }
    mfma_gemm_out<<<gO, 256, 0, stream>>>(hA, woswz, bout, out, N);
}

// Round 2
// 283.166 us; speedup vs baseline: 1.0917x; 1.0044x over previous
//
#include <hip/hip_runtime.h>
#include <hip/hip_bf16.h>
#include <cstddef>

// ---------------------------------------------------------------------------
// 3-layer MPNN, N=50000, E=800000, D=128, OUT=32.
// R14: fused_gemm rewritten W-in-registers (R13's 64KB LDS stage capped
// occupancy at 2 blocks/CU=8 waves/CU -- LOWER than R12's 12, so latency
// stayed exposed; 47->39us only). Now: column-split across waves -- wave w
// holds B-frags for its 2 column tiles (16 x short8 = 64 VGPR) permanently,
// loops 4 row-groups of 16 rows. No LDS, no barriers, ~116 VGPR,
// launch_bounds(256,4) -> 16 waves/CU, all 782 blocks ~co-resident.
// aggregate_g: 2-edge-deep software pipeline (halves dependent
// csr->row-gather latency chains; mean degree 16 = 2 iters -> 1).
// Binning/CSR unchanged from R12.
//   g = Sigma_in w*h[src]; h' = tanh([g|h]@[Wm;Wu]^T+bu); out = h3@Wout^T+b.
// CSR entry: (src:u16 | w:bf16<<16).
// ---------------------------------------------------------------------------

typedef __attribute__((ext_vector_type(8))) short short8;
typedef __attribute__((ext_vector_type(4))) float f32x4;
typedef unsigned short ushort_t;
typedef unsigned int uint_t;

#define BSH 8               // bucket shift: 256 nodes per bucket
#define BSZ 256             // nodes per bucket
#define CAPB 6144           // staged entries per bucket (mean 4096, >30 sigma)
#define TSTRIDE 16          // tails counter stride in ints (64B line each)
#define EPB 2048            // edges per bin block

__device__ inline ushort_t f2bf(float f) {  // round-to-nearest-even
    uint_t u = __float_as_uint(f);
    uint_t r = u + 0x7FFFu + ((u >> 16) & 1u);
    return (ushort_t)(r >> 16);
}
__device__ inline float bf_lo(uint_t u) { return __uint_as_float(u << 16); }
__device__ inline float bf_hi(uint_t u) { return __uint_as_float(u & 0xFFFF0000u); }
__device__ inline uint_t packbf(float a, float b) {
    return (uint_t)f2bf(a) | ((uint_t)f2bf(b) << 16);
}

// fast tanh: 1 - 2/(exp2(2*log2e*x)+1); saturates correctly at +-inf.
__device__ inline float fast_tanh(float x) {
    float e = __builtin_amdgcn_exp2f(x * 2.8853900817779268f);
    return 1.f - 2.f * __builtin_amdgcn_rcpf(e + 1.f);
}

// flag=1 -> int32 [2][E]; flag=0 -> int64 [2][E] (vectorized low-word read)
__device__ inline int get_dst(const int* __restrict__ ei, int e, int E, int f) {
    if (f) return ei[E + e];
    return ((const int2*)ei)[(size_t)E + e].x;
}
__device__ inline int get_src(const int* __restrict__ ei, int e, int E, int f) {
    if (f) return ei[e];
    return ((const int2*)ei)[e].x;
}

// ---------------------------------------------------------------------------
// Fused setup: zero tails+cursor | detect idx layout | swizzled bf16 weights
// | x -> bf16.
// wswz[l]: flat ((ct*8+ks)*64+lane)*8+j <- Wcat[(ct*16+(lane&15))][ks*32+
//   (lane>>4)*8+j]  (Wcat = [Wm | Wu], K=256)
// woswz:   flat ((ct*4+ks)*64+lane)*8+j <- Wout[...]  (K=128, ct<2)
// ---------------------------------------------------------------------------
struct SetupArgs {
    const float* Wm0; const float* Wu0;
    const float* Wm1; const float* Wu1;
    const float* Wm2; const float* Wu2;
    const float* Wout;
    const float* x; const int* ei;
    ushort_t* wswz;    // 3 * 32768
    ushort_t* woswz;   // 4096
    ushort_t* xb;      // N*128
    int* tails;        // NB*TSTRIDE + cursor (zeroed together)
    int* flag;
    int N, E, TI;
    int ZT, WB, XB;
};
__global__ __launch_bounds__(256) void setup_kernel(SetupArgs a) {
    int bx = blockIdx.x, t = threadIdx.x;
    if (bx < a.ZT) {
        int i = bx * 256 + t;
        if (i < a.TI) a.tails[i] = 0;
        return;
    }
    bx -= a.ZT;
    if (bx == 0) {
        __shared__ int any;
        if (t == 0) any = 0;
        __syncthreads();
        int n = a.E < 2048 ? a.E : 2048;
        for (int i = t; i < n; i += 256)
            if (a.ei[2 * i + 1] != 0) any = 1;
        __syncthreads();
        if (t == 0) a.flag[0] = any;
        return;
    }
    bx -= 1;
    if (bx < a.WB) {
        int i = bx * 256 + t;
        if (i < 3 * 32768) {
            int l = i >> 15, r2 = i & 32767;
            int ct = r2 >> 12, ks = (r2 >> 9) & 7, lane = (r2 >> 3) & 63, j = r2 & 7;
            int col = ct * 16 + (lane & 15);
            int k = ks * 32 + (lane >> 4) * 8 + j;
            const float* Wm = l == 0 ? a.Wm0 : (l == 1 ? a.Wm1 : a.Wm2);
            const float* Wu = l == 0 ? a.Wu0 : (l == 1 ? a.Wu1 : a.Wu2);
            float v = k < 128 ? Wm[col * 128 + k] : Wu[col * 128 + (k - 128)];
            a.wswz[(size_t)l * 32768 + r2] = f2bf(v);
        } else if (i < 3 * 32768 + 4096) {
            int r2 = i - 3 * 32768;
            int ct = r2 >> 11, ks = (r2 >> 9) & 3, lane = (r2 >> 3) & 63, j = r2 & 7;
            int col = ct * 16 + (lane & 15);
            int k = ks * 32 + (lane >> 4) * 8 + j;
            a.woswz[r2] = f2bf(a.Wout[col * 128 + k]);
        }
        return;
    }
    bx -= a.WB;
    {
        int j = bx * 256 + t;
        if (j < a.N * 32) {
            float4 v = *(const float4*)(a.x + (size_t)j * 4);
            uint2 o;
            o.x = packbf(v.x, v.y);
            o.y = packbf(v.z, v.w);
            *(uint2*)(a.xb + (size_t)j * 4) = o;
        }
    }
}

// ---------------------------------------------------------------------------
// Phase A: LDS multi-split binning (one global atomic per (block,bucket)).
// bucket = dst>>8 (256 nodes). ~77k reserve atomics total.
// ---------------------------------------------------------------------------
__global__ __launch_bounds__(256) void bin_kernel(
    const int* __restrict__ ei, const float* __restrict__ ew,
    const int* __restrict__ flag, int* __restrict__ tails,
    uint2* __restrict__ staged, int E, int NB) {
    __shared__ uint2 ent[EPB];           // 16 KB
    __shared__ int cnt[256], cur[256], runbase[256];
    const int tid = threadIdx.x;
    const int e0 = blockIdx.x * EPB;
    const int nE = (E - e0) < EPB ? (E - e0) : EPB;
    const int f = flag[0];
    cnt[tid] = 0;
    cur[tid] = 0;
    __syncthreads();
    for (int i = tid; i < nE; i += 256) {
        int e = e0 + i;
        int s = get_src(ei, e, E, f);
        int d = get_dst(ei, e, E, f);
        uint2 v;
        v.x = (uint_t)s | ((uint_t)f2bf(ew[e]) << 16);
        v.y = (uint_t)d;
        ent[i] = v;
        atomicAdd(&cnt[d >> BSH], 1);    // LDS atomic
    }
    __syncthreads();
    if (tid < NB) {
        int c = cnt[tid];
        runbase[tid] = c ? atomicAdd(&tails[tid * TSTRIDE], c) : 0;
    }
    __syncthreads();
    for (int i = tid; i < nE; i += 256) {
        uint2 v = ent[i];
        int d = (int)v.y;
        int b = d >> BSH;
        int lp = atomicAdd(&cur[b], 1);  // LDS atomic
        int gp = runbase[b] + lp;
        if (gp < CAPB) {
            uint2 o;
            o.x = v.x;
            o.y = (uint_t)(d & (BSZ - 1));
            staged[(size_t)b * CAPB + gp] = o;
        }
    }
}

// ---------------------------------------------------------------------------
// Phase B: one block per bucket. Self-allocates the bucket's contiguous CSR
// region via a global cursor (bucket order arbitrary -- only rowspans
// matter). LDS hist (256 nodes) -> LDS excl scan -> LDS image -> coalesced
// flush. Writes rowdeg[node] = int2{beg, end}.
// ---------------------------------------------------------------------------
__global__ __launch_bounds__(256) void place_kernel(
    const uint2* __restrict__ staged, const int* __restrict__ tails,
    int* __restrict__ cursor, uint_t* __restrict__ csr,
    int2* __restrict__ rowdeg, int N) {
    __shared__ int cnt[256], cur[256], excl[256], sm[256];
    __shared__ int baseSh;
    __shared__ uint_t outb[CAPB];        // 24 KB
    const int b = blockIdx.x, tid = threadIdx.x;
    const int node0 = b << BSH;
    int tot = tails[b * TSTRIDE];
    tot = tot < CAPB ? tot : CAPB;
    cnt[tid] = 0;
    __syncthreads();
    const uint2* sp = staged + ((size_t)b * CAPB);
    for (int i = tid; i < tot; i += 256) atomicAdd(&cnt[sp[i].y], 1);
    __syncthreads();
    int c0 = cnt[tid];
    sm[tid] = c0;
    __syncthreads();
    for (int o = 1; o < 256; o <<= 1) {
        int v = tid >= o ? sm[tid - o] : 0;
        __syncthreads();
        sm[tid] += v;
        __syncthreads();
    }
    if (tid == 255) baseSh = atomicAdd(cursor, sm[255]);
    excl[tid] = sm[tid] - c0;
    cur[tid] = 0;
    __syncthreads();
    const int base = baseSh;
    for (int i = tid; i < tot; i += 256) {
        uint2 e = sp[i];
        int pos = excl[e.y] + atomicAdd(&cur[e.y], 1);
        outb[pos] = e.x;
    }
    __syncthreads();
    for (int i = tid; i < tot; i += 256) csr[base + i] = outb[i];
    if (node0 + tid < N) {
        int2 be;
        be.x = base + excl[tid];
        be.y = base + excl[tid] + c0;
        rowdeg[node0 + tid] = be;
    }
}

// ---------------------------------------------------------------------------
// Aggregate: g[d] = Sigma_{in(d)} w*h[src]. One 64-lane wave per node.
// lane = slot(0..7)*8 + f8(0..7); lane owns 16 feats via 2x uint4 loads.
// R14: 2-edge-deep pipeline (independent gather chains, mean deg 16 -> one
// double iteration instead of two dependent ones).
// ---------------------------------------------------------------------------
__global__ __launch_bounds__(256) void aggregate_g(
    const uint_t* __restrict__ csr, const int2* __restrict__ rowdeg,
    const ushort_t* __restrict__ h, ushort_t* __restrict__ g, int N) {
    int node = (blockIdx.x * 256 + threadIdx.x) >> 6;
    if (node >= N) return;
    int lane = threadIdx.x & 63;
    int slot = lane >> 3, f8 = lane & 7;
    int2 be = rowdeg[node];
    int beg = be.x, end = be.y;
    float s[16];
#pragma unroll
    for (int k = 0; k < 16; ++k) s[k] = 0.f;
    int j = beg + slot;
    for (; j + 8 < end; j += 16) {
        uint_t p0 = csr[j];
        uint_t p1 = csr[j + 8];
        float w0 = bf_hi(p0), w1 = bf_hi(p1);
        const ushort_t* r0 = h + (size_t)(p0 & 0xFFFFu) * 128 + f8 * 16;
        const ushort_t* r1 = h + (size_t)(p1 & 0xFFFFu) * 128 + f8 * 16;
        uint4 v0 = *(const uint4*)(r0);
        uint4 v1 = *(const uint4*)(r0 + 8);
        uint4 u0 = *(const uint4*)(r1);
        uint4 u1 = *(const uint4*)(r1 + 8);
        s[0] += w0 * bf_lo(v0.x);  s[1] += w0 * bf_hi(v0.x);
        s[2] += w0 * bf_lo(v0.y);  s[3] += w0 * bf_hi(v0.y);
        s[4] += w0 * bf_lo(v0.z);  s[5] += w0 * bf_hi(v0.z);
        s[6] += w0 * bf_lo(v0.w);  s[7] += w0 * bf_hi(v0.w);
        s[8] += w0 * bf_lo(v1.x);  s[9] += w0 * bf_hi(v1.x);
        s[10] += w0 * bf_lo(v1.y); s[11] += w0 * bf_hi(v1.y);
        s[12] += w0 * bf_lo(v1.z); s[13] += w0 * bf_hi(v1.z);
        s[14] += w0 * bf_lo(v1.w); s[15] += w0 * bf_hi(v1.w);
        s[0] += w1 * bf_lo(u0.x);  s[1] += w1 * bf_hi(u0.x);
        s[2] += w1 * bf_lo(u0.y);  s[3] += w1 * bf_hi(u0.y);
        s[4] += w1 * bf_lo(u0.z);  s[5] += w1 * bf_hi(u0.z);
        s[6] += w1 * bf_lo(u0.w);  s[7] += w1 * bf_hi(u0.w);
        s[8] += w1 * bf_lo(u1.x);  s[9] += w1 * bf_hi(u1.x);
        s[10] += w1 * bf_lo(u1.y); s[11] += w1 * bf_hi(u1.y);
        s[12] += w1 * bf_lo(u1.z); s[13] += w1 * bf_hi(u1.z);
        s[14] += w1 * bf_lo(u1.w); s[15] += w1 * bf_hi(u1.w);
    }
    if (j < end) {
        uint_t p = csr[j];
        float w = bf_hi(p);
        const ushort_t* row = h + (size_t)(p & 0xFFFFu) * 128 + f8 * 16;
        uint4 v0 = *(const uint4*)(row);
        uint4 v1 = *(const uint4*)(row + 8);
        s[0] += w * bf_lo(v0.x);  s[1] += w * bf_hi(v0.x);
        s[2] += w * bf_lo(v0.y);  s[3] += w * bf_hi(v0.y);
        s[4] += w * bf_lo(v0.z);  s[5] += w * bf_hi(v0.z);
        s[6] += w * bf_lo(v0.w);  s[7] += w * bf_hi(v0.w);
        s[8] += w * bf_lo(v1.x);  s[9] += w * bf_hi(v1.x);
        s[10] += w * bf_lo(v1.y); s[11] += w * bf_hi(v1.y);
        s[12] += w * bf_lo(v1.z); s[13] += w * bf_hi(v1.z);
        s[14] += w * bf_lo(v1.w); s[15] += w * bf_hi(v1.w);
    }
#pragma unroll
    for (int k = 0; k < 16; ++k) s[k] += __shfl_xor(s[k], 8, 64);
#pragma unroll
    for (int k = 0; k < 16; ++k) s[k] += __shfl_xor(s[k], 16, 64);
#pragma unroll
    for (int k = 0; k < 16; ++k) s[k] += __shfl_xor(s[k], 32, 64);
    if (slot == 0) {
        uint4 o0, o1;
        o0.x = packbf(s[0], s[1]);   o0.y = packbf(s[2], s[3]);
        o0.z = packbf(s[4], s[5]);   o0.w = packbf(s[6], s[7]);
        o1.x = packbf(s[8], s[9]);   o1.y = packbf(s[10], s[11]);
        o1.z = packbf(s[12], s[13]); o1.w = packbf(s[14], s[15]);
        ushort_t* gp = g + (size_t)node * 128 + f8 * 16;
        *(uint4*)(gp) = o0;
        *(uint4*)(gp + 8) = o1;
    }
}

// ---------------------------------------------------------------------------
// Layer GEMM: Hout[N,128] = tanh([G|H][N,256] @ Wswz + bu).
// R14: W-in-registers, column-split across waves. Block 256 = 4 waves; block
// owns 64 rows; wave w owns cols [w*32, w*32+32) via ct tiles {2w, 2w+1}.
// Wave holds its 16 B-frags (64 VGPR) for the whole kernel; loops 4
// row-groups of 16 rows. No LDS, no barriers; ~116 VGPR -> 16 waves/CU;
// all 782 blocks ~co-resident.
// ---------------------------------------------------------------------------
__global__ __launch_bounds__(256, 4) void fused_gemm(
    const ushort_t* __restrict__ G, const ushort_t* __restrict__ H,
    const ushort_t* __restrict__ Wswz, const float* __restrict__ bias,
    ushort_t* __restrict__ Hout, int N) {
    const int tid = threadIdx.x;
    const int lane = tid & 63;
    const int wave = tid >> 6;
    const int row0 = blockIdx.x * 64;
    const int m = lane & 15, kg = lane >> 4;
    const int colL = lane & 15, rq = lane >> 4;

    // wave's two column tiles, B-fragments held in registers (16 x short8)
    short8 b[2][8];
#pragma unroll
    for (int c = 0; c < 2; ++c)
#pragma unroll
        for (int ksp = 0; ksp < 8; ++ksp)
            b[c][ksp] = *(const short8*)(Wswz + (((2 * wave + c) * 8 + ksp) * 64 + lane) * 8);

    const float bv0 = bias[(2 * wave) * 16 + colL];
    const float bv1 = bias[(2 * wave + 1) * 16 + colL];

#pragma unroll
    for (int gblk = 0; gblk < 4; ++gblk) {
        const int r = row0 + gblk * 16 + m;
        const ushort_t* ag = G + (size_t)r * 128 + kg * 8;
        const ushort_t* ah = H + (size_t)r * 128 + kg * 8;
        short8 a[8];
#pragma unroll
        for (int ks = 0; ks < 4; ++ks) a[ks] = *(const short8*)(ag + ks * 32);
#pragma unroll
        for (int ks = 0; ks < 4; ++ks) a[4 + ks] = *(const short8*)(ah + ks * 32);

        f32x4 acc0 = (f32x4){0.f, 0.f, 0.f, 0.f};
        f32x4 acc1 = (f32x4){0.f, 0.f, 0.f, 0.f};
#pragma unroll
        for (int ksp = 0; ksp < 8; ++ksp) {
            acc0 = __builtin_amdgcn_mfma_f32_16x16x32_bf16(a[ksp], b[0][ksp], acc0, 0, 0, 0);
            acc1 = __builtin_amdgcn_mfma_f32_16x16x32_bf16(a[ksp], b[1][ksp], acc1, 0, 0, 0);
        }
#pragma unroll
        for (int reg = 0; reg < 4; ++reg) {
            int gr = row0 + gblk * 16 + rq * 4 + reg;
            if (gr < N) {
                Hout[(size_t)gr * 128 + (2 * wave) * 16 + colL] = f2bf(fast_tanh(acc0[reg] + bv0));
                Hout[(size_t)gr * 128 + (2 * wave + 1) * 16 + colL] = f2bf(fast_tanh(acc1[reg] + bv1));
            }
        }
    }
}

// LDS-free output GEMM: out[N,32] = H[N,128] @ Woswz + bout (fp32).
// All A/B loads hoisted (8 loads in flight instead of 1).
__global__ __launch_bounds__(256) void mfma_gemm_out(
    const ushort_t* __restrict__ H, const ushort_t* __restrict__ Wswz,
    const float* __restrict__ bias, float* __restrict__ C, int N) {
    const int tid = threadIdx.x;
    const int lane = tid & 63;
    const int row0 = blockIdx.x * 64 + (tid >> 6) * 16;
    const int m = lane & 15;
    const ushort_t* ah = H + (size_t)(row0 + m) * 128 + (lane >> 4) * 8;

    short8 a[4], b[8];
#pragma unroll
    for (int ks = 0; ks < 4; ++ks) a[ks] = *(const short8*)(ah + ks * 32);
#pragma unroll
    for (int ks = 0; ks < 4; ++ks) {
#pragma unroll
        for (int ct = 0; ct < 2; ++ct)
            b[ks * 2 + ct] = *(const short8*)(Wswz + ((ct * 4 + ks) * 64 + lane) * 8);
    }

    f32x4 acc[2];
#pragma unroll
    for (int ct = 0; ct < 2; ++ct) acc[ct] = (f32x4){0.f, 0.f, 0.f, 0.f};
#pragma unroll
    for (int ks = 0; ks < 4; ++ks) {
#pragma unroll
        for (int ct = 0; ct < 2; ++ct)
            acc[ct] = __builtin_amdgcn_mfma_f32_16x16x32_bf16(a[ks], b[ks * 2 + ct], acc[ct], 0, 0, 0);
    }
    const int colL = lane & 15, rq = lane >> 4;
#pragma unroll
    for (int ct = 0; ct < 2; ++ct) {
        int col = ct * 16 + colL;
        float bv = bias[col];
#pragma unroll
        for (int reg = 0; reg < 4; ++reg) {
            int gr = row0 + rq * 4 + reg;
            if (gr < N) C[(size_t)gr * 32 + col] = acc[ct][reg] + bv;
        }
    }
}

extern "C" void kernel_launch(void* const* d_in, const int* in_sizes, int n_in,
                              void* d_out, int out_size, void* d_ws, size_t ws_size,
                              hipStream_t stream) {
    const float* x   = (const float*)d_in[0];
    const int* ei    = (const int*)d_in[1];
    const float* ew  = (const float*)d_in[2];
    const float* Wm[3] = {(const float*)d_in[3], (const float*)d_in[6], (const float*)d_in[9]};
    const float* Wu[3] = {(const float*)d_in[4], (const float*)d_in[7], (const float*)d_in[10]};
    const float* bu[3] = {(const float*)d_in[5], (const float*)d_in[8], (const float*)d_in[11]};
    const float* Wout = (const float*)d_in[12];
    const float* bout = (const float*)d_in[13];
    float* out = (float*)d_out;

    const int N = in_sizes[0] / 128;
    const int E = in_sizes[2];
    const size_t NPAD = 50048;
    const int NB = (N + BSZ - 1) / BSZ;  // 196 buckets
    const int TI = NB * TSTRIDE + 16;    // tails + cursor (zeroed together)

    ushort_t* xb    = (ushort_t*)d_ws;              // [NPAD,128] bf16
    ushort_t* hA    = xb + NPAD * 128;
    ushort_t* hB    = hA + NPAD * 128;
    ushort_t* gbuf  = hB + NPAD * 128;
    ushort_t* wswz  = gbuf + NPAD * 128;            // 3*32768 bf16
    ushort_t* woswz = wswz + 3 * 32768;             // 4096 bf16
    int* flag       = (int*)(woswz + 4096);
    int* tails      = flag + 1;
    int* cursor     = tails + NB * TSTRIDE;         // inside zeroed TI range
    int* endp       = tails + TI;
    int2* rowdeg    = (int2*)(((uintptr_t)endp + 7) & ~(uintptr_t)7);
    uint2* staged   = (uint2*)(rowdeg + N + 8);
    uint_t* csr     = (uint_t*)(staged + (size_t)NB * CAPB);
    (void)ws_size;

    const int ZT = (TI + 255) / 256;
    const int WB = (3 * 32768 + 4096 + 255) / 256;  // 400
    const int XB = (N * 32 + 255) / 256;            // 6250
    const int gB = (E + EPB - 1) / EPB;             // 391
    const int gG = (N + 63) / 64;                   // 782
    const int gA = (N + 3) / 4;                     // 12500
    const int gO = (N + 63) / 64;                   // 782

    SetupArgs sa;
    sa.Wm0 = Wm[0]; sa.Wu0 = Wu[0];
    sa.Wm1 = Wm[1]; sa.Wu1 = Wu[1];
    sa.Wm2 = Wm[2]; sa.Wu2 = Wu[2];
    sa.Wout = Wout; sa.x = x; sa.ei = ei;
    sa.wswz = wswz; sa.woswz = woswz; sa.xb = xb;
    sa.tails = tails; sa.flag = flag;
    sa.N = N; sa.E = E; sa.TI = TI;
    sa.ZT = ZT; sa.WB = WB; sa.XB = XB;
    setup_kernel<<<ZT + 1 + WB + XB, 256, 0, stream>>>(sa);

    bin_kernel<<<gB, 256, 0, stream>>>(ei, ew, flag, tails, staged, E, NB);
    place_kernel<<<NB, 256, 0, stream>>>(staged, tails, cursor, csr, rowdeg, N);

    const ushort_t* hin[3] = {xb, hA, hB};
    ushort_t* hout[3] = {hA, hB, hA};
    for (int l = 0; l < 3; ++l) {
        aggregate_g<<<gA, 256, 0, stream>>>(csr, rowdeg, hin[l], gbuf, N);
        fused_gemm<<<gG, 256, 0, stream>>>(gbuf, hin[l], wswz + (size_t)l * 32768,
                                           bu[l], hout[l], N);
    }
    mfma_gemm_out<<<gO, 256, 0, stream>>>(hA, woswz, bout, out, N);
}